// Round 5
// baseline (656.170 us; speedup 1.0000x reference)
//
#include <hip/hip_runtime.h>
#include <hip/hip_bf16.h>

// ---------------- X0 = ent_tab[entity] ----------------
__global__ __launch_bounds__(256) void x0_kernel(
    const float* __restrict__ tab, const int* __restrict__ entity,
    float* __restrict__ X0, int N)
{
    int idx = blockIdx.x * 256 + threadIdx.x;   // one float4 per thread
    int n = idx >> 5, l = idx & 31;
    if (n < N) {
        int src = entity[n];
        *(float4*)&X0[(size_t)n * 128 + l * 4] =
            *(const float4*)&tab[(size_t)src * 128 + l * 4];
    }
}

// ---------------- CSR build ----------------
__global__ __launch_bounds__(256) void hist_kernel(
    const int* __restrict__ edge_index, int* __restrict__ deg, int E)
{
    int e = blockIdx.x * 256 + threadIdx.x;
    if (e < E) atomicAdd(&deg[edge_index[E + e]], 1);
}

__global__ __launch_bounds__(1024) void scan_kernel(
    const int* __restrict__ deg, int* __restrict__ row_start,
    int* __restrict__ cursor, int N)
{
    __shared__ int wtot[16];
    __shared__ int woff[16];
    __shared__ int carry;
    const int tid = threadIdx.x, lane = tid & 63, wid = tid >> 6;
    if (tid == 0) carry = 0;
    __syncthreads();
    const int nChunks = (N + 1023) / 1024;
    for (int c = 0; c < nChunks; ++c) {
        int i = c * 1024 + tid;
        int v = (i < N) ? deg[i] : 0;
        int x = v;
        #pragma unroll
        for (int d = 1; d < 64; d <<= 1) {
            int t = __shfl_up(x, d, 64);
            if (lane >= d) x += t;
        }
        if (lane == 63) wtot[wid] = x;
        __syncthreads();
        if (wid == 0 && lane < 16) {
            int s = wtot[lane];
            int y = s;
            #pragma unroll
            for (int d = 1; d < 16; d <<= 1) {
                int t = __shfl_up(y, d, 16);
                if (lane >= d) y += t;
            }
            woff[lane] = y - s;
            if (lane == 15) wtot[15] = y;
        }
        __syncthreads();
        if (i < N) {
            int rs = carry + woff[wid] + (x - v);
            row_start[i] = rs;
            cursor[i]    = rs;
        }
        __syncthreads();
        if (tid == 0) carry += wtot[15];
        __syncthreads();
    }
    if (tid == 0) row_start[N] = carry;
}

__global__ __launch_bounds__(256) void fill_kernel(
    const int* __restrict__ edge_index, const int* __restrict__ edge_type,
    const float* __restrict__ edge_norm, int* __restrict__ cursor,
    int* __restrict__ src_s, int* __restrict__ et_s, float* __restrict__ norm_s, int E)
{
    int e = blockIdx.x * 256 + threadIdx.x;
    if (e >= E) return;
    int dst = edge_index[E + e];
    int pos = atomicAdd(&cursor[dst], 1);
    src_s[pos]  = edge_index[e];
    et_s[pos]   = edge_type[e];
    norm_s[pos] = edge_norm[e];
}

// ---------------- edge aggregation: w[n, 4d+b] = (sum_e norm*att[et,b]*x[src,d])/cnt
__global__ __launch_bounds__(256) void edge_agg_kernel(
    const float* __restrict__ X,        // [N,128] layer input
    const int* __restrict__ row_start,
    const int* __restrict__ src_s, const int* __restrict__ et_s,
    const float* __restrict__ norm_s,
    const float* __restrict__ att,      // [R,4]
    float* __restrict__ w, int N)
{
    int n = blockIdx.x * 2 + (threadIdx.x >> 7);
    if (n >= N) return;
    int o = threadIdx.x & 127;          // input dim d
    int s0 = row_start[n], s1 = row_start[n + 1];
    float w0 = 0.f, w1 = 0.f, w2 = 0.f, w3 = 0.f;
    for (int p = s0; p < s1; ++p) {
        int   src  = src_s[p];
        int   et   = et_s[p];
        float norm = norm_s[p];
        float4 a = *(const float4*)(att + (size_t)et * 4);
        float xv = X[(size_t)src * 128 + o];
        w0 = fmaf(norm * a.x, xv, w0);
        w1 = fmaf(norm * a.y, xv, w1);
        w2 = fmaf(norm * a.z, xv, w2);
        w3 = fmaf(norm * a.w, xv, w3);
    }
    float inv = 1.0f / fmaxf((float)(s1 - s0), 1.0f);
    *(float4*)&w[(size_t)n * 512 + (o << 2)] =
        make_float4(w0 * inv, w1 * inv, w2 * inv, w3 * inv);
}

// ---------------- GEMM K=640: Xout[n,o] = relu([w|X] @ [basis_stacked|root] + bias)
// 64x128 tile, 256 threads, 4x8 per-thread block, K-chunks of 32.
// As [k][m] stride 68 (16B-aligned, conflict-free broadcast reads), Bs [k][o].
__global__ __launch_bounds__(256, 4) void gemm640_kernel(
    const float* __restrict__ w,        // [N,512] (k = 4d+b)
    const float* __restrict__ X,        // [N,128] (root input)
    const float* __restrict__ basis,    // [4,128,128]
    const float* __restrict__ root,     // [128,128]
    const float* __restrict__ bias,     // [128]
    float* Xout, int N)
{
    __shared__ float As[32 * 68];
    __shared__ float Bs[32 * 128];

    const int tid  = threadIdx.x;
    const int row0 = blockIdx.x * 64;

    const int rg = tid >> 4;            // rows rg*4..rg*4+3
    const int cg = tid & 15;
    const int cA = cg << 2;             // cols cA..cA+3 and 64+cA..64+cA+3

    float acc[4][8];
    #pragma unroll
    for (int j = 0; j < 4; ++j)
        #pragma unroll
        for (int c = 0; c < 8; ++c) acc[j][c] = 0.0f;

    for (int kc = 0; kc < 20; ++kc) {
        const int k0 = kc * 32;
        if (kc) __syncthreads();

        // A chunk: 64 rows x 32 k (rows from w for k<512, X for k>=512)
        #pragma unroll
        for (int i = 0; i < 2; ++i) {
            int idx = tid + i * 256;     // 0..511
            int r   = idx >> 3;          // 0..63
            int kv  = (idx & 7) << 2;    // 0..28
            int gr  = row0 + r;
            float4 v = make_float4(0.f, 0.f, 0.f, 0.f);
            if (gr < N) {
                if (k0 < 512) v = *(const float4*)&w[(size_t)gr * 512 + k0 + kv];
                else          v = *(const float4*)&X[(size_t)gr * 128 + (k0 - 512) + kv];
            }
            As[(kv + 0) * 68 + r] = v.x;
            As[(kv + 1) * 68 + r] = v.y;
            As[(kv + 2) * 68 + r] = v.z;
            As[(kv + 3) * 68 + r] = v.w;
        }
        // B chunk: 32 k x 128 o; k=4d+b -> basis[b][d][o], k>=512 -> root[k-512][o]
        #pragma unroll
        for (int i = 0; i < 4; ++i) {
            int idx = tid + i * 256;
            int kl  = idx >> 5;          // 0..31
            int ov  = (idx & 31) << 2;   // 0..124
            int kg  = k0 + kl;
            float4 wt;
            if (kg < 512) wt = *(const float4*)&basis[((kg & 3) << 14) + ((kg >> 2) << 7) + ov];
            else          wt = *(const float4*)&root[((kg - 512) << 7) + ov];
            *(float4*)&Bs[kl * 128 + ov] = wt;
        }
        __syncthreads();

        #pragma unroll 4
        for (int k = 0; k < 32; ++k) {
            float a[4], b[8];
            *(float4*)&a[0] = *(const float4*)&As[k * 68 + (rg << 2)];
            *(float4*)&b[0] = *(const float4*)&Bs[k * 128 + cA];
            *(float4*)&b[4] = *(const float4*)&Bs[k * 128 + 64 + cA];
            #pragma unroll
            for (int j = 0; j < 4; ++j)
                #pragma unroll
                for (int c = 0; c < 8; ++c)
                    acc[j][c] = fmaf(a[j], b[c], acc[j][c]);
        }
    }

    float4 bi0 = *(const float4*)&bias[cA];
    float4 bi1 = *(const float4*)&bias[64 + cA];
    #pragma unroll
    for (int j = 0; j < 4; ++j) {
        int gr = row0 + (rg << 2) + j;
        if (gr < N) {
            float* yp = Xout + (size_t)gr * 128;
            *(float4*)(yp + cA) = make_float4(
                fmaxf(acc[j][0] + bi0.x, 0.f), fmaxf(acc[j][1] + bi0.y, 0.f),
                fmaxf(acc[j][2] + bi0.z, 0.f), fmaxf(acc[j][3] + bi0.w, 0.f));
            *(float4*)(yp + 64 + cA) = make_float4(
                fmaxf(acc[j][4] + bi1.x, 0.f), fmaxf(acc[j][5] + bi1.y, 0.f),
                fmaxf(acc[j][6] + bi1.z, 0.f), fmaxf(acc[j][7] + bi1.w, 0.f));
        }
    }
}

// ---------------- relation context (tiny) ----------------
__global__ __launch_bounds__(128) void relctx_kernel(
    const float* __restrict__ DAD,
    const float* __restrict__ tab,
    const float* __restrict__ W,
    float* __restrict__ R2, int NR)
{
    int r = blockIdx.x;
    int o = threadIdx.x;
    float s = 0.0f;
    for (int j = 0; j < NR; ++j)
        s = fmaf(DAD[r * NR + j], tab[j * 128 + o], s);
    __shared__ float r1s[128];
    r1s[o] = s;
    __syncthreads();
    float s2 = 0.0f;
    #pragma unroll 8
    for (int k = 0; k < 128; ++k)
        s2 = fmaf(r1s[k], W[k * 128 + o], s2);
    R2[r * 128 + o] = fmaxf(s2, 0.0f);
}

// ---------------- gated output ----------------
__global__ __launch_bounds__(256) void output_kernel(
    const int* __restrict__ samples,
    const float* __restrict__ gate_e,
    const float* __restrict__ gate_r,
    const float* __restrict__ ent_emb,
    const float* __restrict__ rel_emb,
    const float* __restrict__ ctx2,
    const float* __restrict__ relctx,
    float* __restrict__ out, int S)
{
    int s = blockIdx.x * 2 + (threadIdx.x >> 7);
    if (s >= S) return;
    int p = blockIdx.y;
    int o = threadIdx.x & 127;
    float v;
    if (p == 1) {
        int idx = samples[s * 3 + 1];
        float g = 1.0f / (1.0f + __expf(-gate_r[o]));
        v = g * rel_emb[idx * 128 + o] + (1.0f - g) * relctx[idx * 128 + o];
    } else {
        int idx = samples[s * 3 + (p == 0 ? 0 : 2)];
        float g = 1.0f / (1.0f + __expf(-gate_e[o]));
        v = g * ent_emb[(size_t)idx * 128 + o] + (1.0f - g) * ctx2[(size_t)idx * 128 + o];
    }
    out[(size_t)p * S * 128 + (size_t)s * 128 + o] = v;
}

extern "C" void kernel_launch(void* const* d_in, const int* in_sizes, int n_in,
                              void* d_out, int out_size, void* d_ws, size_t ws_size,
                              hipStream_t stream)
{
    const int*   entity     = (const int*)d_in[0];
    const int*   edge_index = (const int*)d_in[1];
    const int*   edge_type  = (const int*)d_in[2];
    const float* edge_norm  = (const float*)d_in[3];
    const int*   samples    = (const int*)d_in[4];
    const float* DAD        = (const float*)d_in[5];
    const float* ent_emb    = (const float*)d_in[6];
    const float* rel_emb    = (const float*)d_in[7];
    const float* ent_tab    = (const float*)d_in[8];
    const float* rel_tab    = (const float*)d_in[9];
    const float* Wrel       = (const float*)d_in[10];
    const float* gate_e     = (const float*)d_in[11];
    const float* gate_r     = (const float*)d_in[12];
    const float* basis1     = (const float*)d_in[13];
    const float* att1       = (const float*)d_in[14];
    const float* root1      = (const float*)d_in[15];
    const float* bias1      = (const float*)d_in[16];
    const float* basis2     = (const float*)d_in[17];
    const float* att2       = (const float*)d_in[18];
    const float* root2      = (const float*)d_in[19];
    const float* bias2      = (const float*)d_in[20];

    const int N  = in_sizes[0];        // 50000
    const int E  = in_sizes[2];        // 200000
    const int S  = in_sizes[4] / 3;    // 20000
    const int NR = in_sizes[9] / 128;  // 200

    float* ws      = (float*)d_ws;
    float* X0      = ws;                               // [N,128]
    float* X1      = X0 + (size_t)N * 128;             // [N,128]
    float* w       = X1 + (size_t)N * 128;             // [N,512]
    float* Rc      = w + (size_t)N * 512;              // [NR,128]
    int*   deg     = (int*)(Rc + (size_t)NR * 128);    // [N]
    int*   rstart  = deg + N;                          // [N+1]
    int*   cursor  = rstart + N + 1;                   // [N]
    int*   src_s   = cursor + N;                       // [E]
    int*   et_s    = src_s + E;                        // [E]
    float* norm_s  = (float*)(et_s + E);               // [E]

    const int egrid = (E + 255) / 256;
    const int ggrid = (N + 63) / 64;
    const int agrid = (N + 1) / 2;

    // ---- CSR build ----
    hipMemsetAsync(deg, 0, (size_t)N * sizeof(int), stream);
    hist_kernel<<<egrid, 256, 0, stream>>>(edge_index, deg, E);
    scan_kernel<<<1, 1024, 0, stream>>>(deg, rstart, cursor, N);
    fill_kernel<<<egrid, 256, 0, stream>>>(edge_index, edge_type, edge_norm, cursor,
                                           src_s, et_s, norm_s, E);

    // ---- X0 = ent_tab[entity] ----
    x0_kernel<<<(N * 32 + 255) / 256, 256, 0, stream>>>(ent_tab, entity, X0, N);

    // ---- layer 1: X1 = relu([agg(X0) | X0] @ W1) ----
    edge_agg_kernel<<<agrid, 256, 0, stream>>>(X0, rstart, src_s, et_s, norm_s, att1, w, N);
    gemm640_kernel<<<ggrid, 256, 0, stream>>>(w, X0, basis1, root1, bias1, X1, N);

    // ---- layer 2: X0 = relu([agg(X1) | X1] @ W2)  (ping-pong, no aliasing) ----
    edge_agg_kernel<<<agrid, 256, 0, stream>>>(X1, rstart, src_s, et_s, norm_s, att2, w, N);
    gemm640_kernel<<<ggrid, 256, 0, stream>>>(w, X1, basis2, root2, bias2, X0, N);

    // ---- relation context ----
    relctx_kernel<<<NR, 128, 0, stream>>>(DAD, rel_tab, Wrel, Rc, NR);

    // ---- gated output ----
    output_kernel<<<dim3((S + 1) / 2, 3), 256, 0, stream>>>(
        samples, gate_e, gate_r, ent_emb, rel_emb, X0, Rc, (float*)d_out, S);
}

// Round 6
// 502.281 us; speedup vs baseline: 1.3064x; 1.3064x over previous
//
#include <hip/hip_runtime.h>
#include <hip/hip_bf16.h>

typedef short s8v  __attribute__((ext_vector_type(8)));
typedef float f4v  __attribute__((ext_vector_type(4)));
typedef unsigned short us8 __attribute__((ext_vector_type(8)));

__device__ __forceinline__ unsigned short f2bf(float x) {   // RTN-even
    unsigned u = __float_as_uint(x);
    unsigned r = ((u >> 16) & 1u) + 0x7FFFu;
    return (unsigned short)((u + r) >> 16);
}
__device__ __forceinline__ float bf2f(unsigned short h) {
    return __uint_as_float(((unsigned)h) << 16);
}

// ---------------- X0 = ent_tab[entity] ----------------
__global__ __launch_bounds__(256) void x0_kernel(
    const float* __restrict__ tab, const int* __restrict__ entity,
    float* __restrict__ X0, int N)
{
    int idx = blockIdx.x * 256 + threadIdx.x;
    int n = idx >> 5, l = idx & 31;
    if (n < N) {
        int src = entity[n];
        *(float4*)&X0[(size_t)n * 128 + l * 4] =
            *(const float4*)&tab[(size_t)src * 128 + l * 4];
    }
}

// ---------------- B prep: Bt[n][k] hi/lo bf16 for both layers ----------------
// k<512: basis[k&3][k>>2][n]; k>=512: root[k-512][n]
__global__ __launch_bounds__(256) void bprep_kernel(
    const float* __restrict__ basis1, const float* __restrict__ root1,
    const float* __restrict__ basis2, const float* __restrict__ root2,
    unsigned short* __restrict__ Bt1h, unsigned short* __restrict__ Bt1l,
    unsigned short* __restrict__ Bt2h, unsigned short* __restrict__ Bt2l)
{
    int idx = blockIdx.x * 256 + threadIdx.x;    // 0..81919
    int layer = blockIdx.y;
    int n = idx & 127, k = idx >> 7;             // k 0..639
    const float* basis = layer ? basis2 : basis1;
    const float* root  = layer ? root2  : root1;
    float v = (k < 512) ? basis[((k & 3) << 14) + ((k >> 2) << 7) + n]
                        : root[((k - 512) << 7) + n];
    unsigned short h = f2bf(v);
    unsigned short l = f2bf(v - bf2f(h));
    unsigned short* Bh = layer ? Bt2h : Bt1h;
    unsigned short* Bl = layer ? Bt2l : Bt1l;
    Bh[(size_t)n * 640 + k] = h;
    Bl[(size_t)n * 640 + k] = l;
}

// ---------------- CSR build ----------------
__global__ __launch_bounds__(256) void hist_kernel(
    const int* __restrict__ edge_index, int* __restrict__ deg, int E)
{
    int e = blockIdx.x * 256 + threadIdx.x;
    if (e < E) atomicAdd(&deg[edge_index[E + e]], 1);
}

__global__ __launch_bounds__(1024) void scan_kernel(
    const int* __restrict__ deg, int* __restrict__ row_start,
    int* __restrict__ cursor, int N)
{
    __shared__ int wtot[16];
    __shared__ int woff[16];
    __shared__ int carry;
    const int tid = threadIdx.x, lane = tid & 63, wid = tid >> 6;
    if (tid == 0) carry = 0;
    __syncthreads();
    const int nChunks = (N + 1023) / 1024;
    for (int c = 0; c < nChunks; ++c) {
        int i = c * 1024 + tid;
        int v = (i < N) ? deg[i] : 0;
        int x = v;
        #pragma unroll
        for (int d = 1; d < 64; d <<= 1) {
            int t = __shfl_up(x, d, 64);
            if (lane >= d) x += t;
        }
        if (lane == 63) wtot[wid] = x;
        __syncthreads();
        if (wid == 0 && lane < 16) {
            int s = wtot[lane];
            int y = s;
            #pragma unroll
            for (int d = 1; d < 16; d <<= 1) {
                int t = __shfl_up(y, d, 16);
                if (lane >= d) y += t;
            }
            woff[lane] = y - s;
            if (lane == 15) wtot[15] = y;
        }
        __syncthreads();
        if (i < N) {
            int rs = carry + woff[wid] + (x - v);
            row_start[i] = rs;
            cursor[i]    = rs;
        }
        __syncthreads();
        if (tid == 0) carry += wtot[15];
        __syncthreads();
    }
    if (tid == 0) row_start[N] = carry;
}

__global__ __launch_bounds__(256) void fill_kernel(
    const int* __restrict__ edge_index, const int* __restrict__ edge_type,
    const float* __restrict__ edge_norm, int* __restrict__ cursor,
    int* __restrict__ src_s, int* __restrict__ et_s, float* __restrict__ norm_s, int E)
{
    int e = blockIdx.x * 256 + threadIdx.x;
    if (e >= E) return;
    int dst = edge_index[E + e];
    int pos = atomicAdd(&cursor[dst], 1);
    src_s[pos]  = edge_index[e];
    et_s[pos]   = edge_type[e];
    norm_s[pos] = edge_norm[e];
}

// ---------------- edge agg: w[n,4d+b] = (sum_e norm*att[et,b]*x[src,d])/cnt
// 8 nodes/block, 32 lanes/node, float4 per lane.
__global__ __launch_bounds__(256) void edge_agg_kernel(
    const float* __restrict__ X,
    const int* __restrict__ row_start,
    const int* __restrict__ src_s, const int* __restrict__ et_s,
    const float* __restrict__ norm_s,
    const float* __restrict__ att,      // [R,4]
    float* __restrict__ w, int N)
{
    int n = blockIdx.x * 8 + (threadIdx.x >> 5);
    if (n >= N) return;
    int l = threadIdx.x & 31;           // dims 4l..4l+3
    int s0 = row_start[n], s1 = row_start[n + 1];
    float acc[4][4];
    #pragma unroll
    for (int d = 0; d < 4; ++d)
        #pragma unroll
        for (int b = 0; b < 4; ++b) acc[d][b] = 0.f;
    for (int p = s0; p < s1; ++p) {
        int   src  = src_s[p];
        int   et   = et_s[p];
        float norm = norm_s[p];
        float4 a = *(const float4*)(att + (size_t)et * 4);
        a.x *= norm; a.y *= norm; a.z *= norm; a.w *= norm;
        float4 x = *(const float4*)&X[(size_t)src * 128 + (l << 2)];
        float xs[4] = {x.x, x.y, x.z, x.w};
        #pragma unroll
        for (int d = 0; d < 4; ++d) {
            acc[d][0] = fmaf(a.x, xs[d], acc[d][0]);
            acc[d][1] = fmaf(a.y, xs[d], acc[d][1]);
            acc[d][2] = fmaf(a.z, xs[d], acc[d][2]);
            acc[d][3] = fmaf(a.w, xs[d], acc[d][3]);
        }
    }
    float inv = 1.0f / fmaxf((float)(s1 - s0), 1.0f);
    #pragma unroll
    for (int d = 0; d < 4; ++d) {
        *(float4*)&w[(size_t)n * 512 + ((l << 2) + d) * 4] =
            make_float4(acc[d][0] * inv, acc[d][1] * inv, acc[d][2] * inv, acc[d][3] * inv);
    }
}

// ---------------- GEMM K=640 via split-bf16 MFMA ----------------
// Xout[64 rows/block, 128 cols] = relu([w|X] @ Bt^T + bias)
// 4 waves; wave wv: rows [row0+wv*16, +16), 8 n-tiles of 16.
// acc += aLo*bHi + aHi*bLo + aHi*bHi  (lo*lo dropped, ~2^-18)
__global__ __launch_bounds__(256) void gemm640_kernel(
    const float* __restrict__ w,              // [N,512]
    const float* __restrict__ X,              // [N,128]
    const unsigned short* __restrict__ Bth,   // [128][640] bf16 hi
    const unsigned short* __restrict__ Btl,   // [128][640] bf16 lo
    const float* __restrict__ bias,
    float* __restrict__ Xout, int N)
{
    __shared__ unsigned short A_hi[64 * 40];
    __shared__ unsigned short A_lo[64 * 40];
    __shared__ unsigned short B_hi[128 * 40];
    __shared__ unsigned short B_lo[128 * 40];

    const int tid  = threadIdx.x;
    const int row0 = blockIdx.x * 64;
    const int lane = tid & 63, wv = tid >> 6;
    const int ml   = lane & 15, quad = lane >> 4;

    f4v acc[8];
    #pragma unroll
    for (int t = 0; t < 8; ++t) acc[t] = (f4v){0.f, 0.f, 0.f, 0.f};

    for (int kc = 0; kc < 20; ++kc) {
        const int k0 = kc * 32;
        if (kc) __syncthreads();

        // A: 64 rows x 32 k fp32 -> split hi/lo bf16
        #pragma unroll
        for (int i = 0; i < 2; ++i) {
            int idx = tid + i * 256;
            int r = idx >> 3, kv = (idx & 7) << 2;
            int gr = row0 + r;
            float4 v = make_float4(0.f, 0.f, 0.f, 0.f);
            if (gr < N) {
                if (k0 < 512) v = *(const float4*)&w[(size_t)gr * 512 + k0 + kv];
                else          v = *(const float4*)&X[(size_t)gr * 128 + (k0 - 512) + kv];
            }
            ushort4 h, l;
            h.x = f2bf(v.x); l.x = f2bf(v.x - bf2f(h.x));
            h.y = f2bf(v.y); l.y = f2bf(v.y - bf2f(h.y));
            h.z = f2bf(v.z); l.z = f2bf(v.z - bf2f(h.z));
            h.w = f2bf(v.w); l.w = f2bf(v.w - bf2f(h.w));
            *(ushort4*)&A_hi[r * 40 + kv] = h;
            *(ushort4*)&A_lo[r * 40 + kv] = l;
        }
        // B: 128 n x 32 k, straight bf16 copy (hi & lo)
        #pragma unroll
        for (int i = 0; i < 2; ++i) {
            int idx = tid + i * 256;          // 0..511
            int n = idx >> 2, kv = (idx & 3) << 3;
            *(us8*)&B_hi[n * 40 + kv] = *(const us8*)&Bth[(size_t)n * 640 + k0 + kv];
            *(us8*)&B_lo[n * 40 + kv] = *(const us8*)&Btl[(size_t)n * 640 + k0 + kv];
        }
        __syncthreads();

        s8v aH = *(const s8v*)&A_hi[(wv * 16 + ml) * 40 + quad * 8];
        s8v aL = *(const s8v*)&A_lo[(wv * 16 + ml) * 40 + quad * 8];
        #pragma unroll
        for (int t = 0; t < 8; ++t) {
            s8v bH = *(const s8v*)&B_hi[(t * 16 + ml) * 40 + quad * 8];
            s8v bL = *(const s8v*)&B_lo[(t * 16 + ml) * 40 + quad * 8];
            acc[t] = __builtin_amdgcn_mfma_f32_16x16x32_bf16(aL, bH, acc[t], 0, 0, 0);
            acc[t] = __builtin_amdgcn_mfma_f32_16x16x32_bf16(aH, bL, acc[t], 0, 0, 0);
            acc[t] = __builtin_amdgcn_mfma_f32_16x16x32_bf16(aH, bH, acc[t], 0, 0, 0);
        }
    }

    // epilogue: C/D layout col=lane&15, row=quad*4+reg
    #pragma unroll
    for (int t = 0; t < 8; ++t) {
        float bv = bias[t * 16 + ml];
        #pragma unroll
        for (int j = 0; j < 4; ++j) {
            int gr = row0 + wv * 16 + quad * 4 + j;
            if (gr < N)
                Xout[(size_t)gr * 128 + t * 16 + ml] = fmaxf(acc[t][j] + bv, 0.f);
        }
    }
}

// ---------------- relation context (tiny) ----------------
__global__ __launch_bounds__(128) void relctx_kernel(
    const float* __restrict__ DAD,
    const float* __restrict__ tab,
    const float* __restrict__ W,
    float* __restrict__ R2, int NR)
{
    int r = blockIdx.x;
    int o = threadIdx.x;
    float s = 0.0f;
    for (int j = 0; j < NR; ++j)
        s = fmaf(DAD[r * NR + j], tab[j * 128 + o], s);
    __shared__ float r1s[128];
    r1s[o] = s;
    __syncthreads();
    float s2 = 0.0f;
    #pragma unroll 8
    for (int k = 0; k < 128; ++k)
        s2 = fmaf(r1s[k], W[k * 128 + o], s2);
    R2[r * 128 + o] = fmaxf(s2, 0.0f);
}

// ---------------- gated output ----------------
__global__ __launch_bounds__(256) void output_kernel(
    const int* __restrict__ samples,
    const float* __restrict__ gate_e,
    const float* __restrict__ gate_r,
    const float* __restrict__ ent_emb,
    const float* __restrict__ rel_emb,
    const float* __restrict__ ctx2,
    const float* __restrict__ relctx,
    float* __restrict__ out, int S)
{
    int s = blockIdx.x * 2 + (threadIdx.x >> 7);
    if (s >= S) return;
    int p = blockIdx.y;
    int o = threadIdx.x & 127;
    float v;
    if (p == 1) {
        int idx = samples[s * 3 + 1];
        float g = 1.0f / (1.0f + __expf(-gate_r[o]));
        v = g * rel_emb[idx * 128 + o] + (1.0f - g) * relctx[idx * 128 + o];
    } else {
        int idx = samples[s * 3 + (p == 0 ? 0 : 2)];
        float g = 1.0f / (1.0f + __expf(-gate_e[o]));
        v = g * ent_emb[(size_t)idx * 128 + o] + (1.0f - g) * ctx2[(size_t)idx * 128 + o];
    }
    out[(size_t)p * S * 128 + (size_t)s * 128 + o] = v;
}

extern "C" void kernel_launch(void* const* d_in, const int* in_sizes, int n_in,
                              void* d_out, int out_size, void* d_ws, size_t ws_size,
                              hipStream_t stream)
{
    const int*   entity     = (const int*)d_in[0];
    const int*   edge_index = (const int*)d_in[1];
    const int*   edge_type  = (const int*)d_in[2];
    const float* edge_norm  = (const float*)d_in[3];
    const int*   samples    = (const int*)d_in[4];
    const float* DAD        = (const float*)d_in[5];
    const float* ent_emb    = (const float*)d_in[6];
    const float* rel_emb    = (const float*)d_in[7];
    const float* ent_tab    = (const float*)d_in[8];
    const float* rel_tab    = (const float*)d_in[9];
    const float* Wrel       = (const float*)d_in[10];
    const float* gate_e     = (const float*)d_in[11];
    const float* gate_r     = (const float*)d_in[12];
    const float* basis1     = (const float*)d_in[13];
    const float* att1       = (const float*)d_in[14];
    const float* root1      = (const float*)d_in[15];
    const float* bias1      = (const float*)d_in[16];
    const float* basis2     = (const float*)d_in[17];
    const float* att2       = (const float*)d_in[18];
    const float* root2      = (const float*)d_in[19];
    const float* bias2      = (const float*)d_in[20];

    const int N  = in_sizes[0];        // 50000
    const int E  = in_sizes[2];        // 200000
    const int S  = in_sizes[4] / 3;    // 20000
    const int NR = in_sizes[9] / 128;  // 200

    float* ws      = (float*)d_ws;
    float* X0      = ws;                               // [N,128]
    float* X1      = X0 + (size_t)N * 128;             // [N,128]
    float* w       = X1 + (size_t)N * 128;             // [N,512]
    float* Rc      = w + (size_t)N * 512;              // [NR,128]
    int*   deg     = (int*)(Rc + (size_t)NR * 128);    // [N]
    int*   rstart  = deg + N;                          // [N+1]
    int*   cursor  = rstart + N + 1;                   // [N]
    int*   src_s   = cursor + N;                       // [E]
    int*   et_s    = src_s + E;                        // [E]
    float* norm_s  = (float*)(et_s + E);               // [E]
    uintptr_t bt   = ((uintptr_t)(norm_s + E) + 15) & ~(uintptr_t)15;
    unsigned short* Bt1h = (unsigned short*)bt;        // [128*640] each
    unsigned short* Bt1l = Bt1h + 128 * 640;
    unsigned short* Bt2h = Bt1l + 128 * 640;
    unsigned short* Bt2l = Bt2h + 128 * 640;

    const int egrid = (E + 255) / 256;
    const int ggrid = (N + 63) / 64;
    const int agrid = (N + 7) / 8;

    // ---- weight prep + CSR build (independent) ----
    bprep_kernel<<<dim3(320, 2), 256, 0, stream>>>(basis1, root1, basis2, root2,
                                                   Bt1h, Bt1l, Bt2h, Bt2l);
    hipMemsetAsync(deg, 0, (size_t)N * sizeof(int), stream);
    hist_kernel<<<egrid, 256, 0, stream>>>(edge_index, deg, E);
    scan_kernel<<<1, 1024, 0, stream>>>(deg, rstart, cursor, N);
    fill_kernel<<<egrid, 256, 0, stream>>>(edge_index, edge_type, edge_norm, cursor,
                                           src_s, et_s, norm_s, E);

    // ---- X0 = ent_tab[entity] ----
    x0_kernel<<<(N * 32 + 255) / 256, 256, 0, stream>>>(ent_tab, entity, X0, N);

    // ---- layer 1: X1 = relu([agg(X0)|X0] @ W1) ----
    edge_agg_kernel<<<agrid, 256, 0, stream>>>(X0, rstart, src_s, et_s, norm_s, att1, w, N);
    gemm640_kernel<<<ggrid, 256, 0, stream>>>(w, X0, Bt1h, Bt1l, bias1, X1, N);

    // ---- layer 2: X0 = relu([agg(X1)|X1] @ W2) ----
    edge_agg_kernel<<<agrid, 256, 0, stream>>>(X1, rstart, src_s, et_s, norm_s, att2, w, N);
    gemm640_kernel<<<ggrid, 256, 0, stream>>>(w, X1, Bt2h, Bt2l, bias2, X0, N);

    // ---- relation context ----
    relctx_kernel<<<NR, 128, 0, stream>>>(DAD, rel_tab, Wrel, Rc, NR);

    // ---- gated output ----
    output_kernel<<<dim3((S + 1) / 2, 3), 256, 0, stream>>>(
        samples, gate_e, gate_r, ent_emb, rel_emb, X0, Rc, (float*)d_out, S);
}

// Round 7
// 357.446 us; speedup vs baseline: 1.8357x; 1.4052x over previous
//
#include <hip/hip_runtime.h>
#include <hip/hip_bf16.h>

typedef short s8v  __attribute__((ext_vector_type(8)));
typedef float f4v  __attribute__((ext_vector_type(4)));
typedef unsigned short us8 __attribute__((ext_vector_type(8)));

__device__ __forceinline__ unsigned short f2bf(float x) {   // RTN-even
    unsigned u = __float_as_uint(x);
    unsigned r = ((u >> 16) & 1u) + 0x7FFFu;
    return (unsigned short)((u + r) >> 16);
}
__device__ __forceinline__ float bf2f(unsigned short h) {
    return __uint_as_float(((unsigned)h) << 16);
}

// ---------------- X0 = ent_tab[entity] ----------------
__global__ __launch_bounds__(256) void x0_kernel(
    const float* __restrict__ tab, const int* __restrict__ entity,
    float* __restrict__ X0, int N)
{
    int idx = blockIdx.x * 256 + threadIdx.x;
    int n = idx >> 5, l = idx & 31;
    if (n < N) {
        int src = entity[n];
        *(float4*)&X0[(size_t)n * 128 + l * 4] =
            *(const float4*)&tab[(size_t)src * 128 + l * 4];
    }
}

// ---------------- B prep: Bt[n][k] hi/lo bf16 for both layers ----------------
__global__ __launch_bounds__(256) void bprep_kernel(
    const float* __restrict__ basis1, const float* __restrict__ root1,
    const float* __restrict__ basis2, const float* __restrict__ root2,
    unsigned short* __restrict__ Bt1h, unsigned short* __restrict__ Bt1l,
    unsigned short* __restrict__ Bt2h, unsigned short* __restrict__ Bt2l)
{
    int idx = blockIdx.x * 256 + threadIdx.x;    // 0..81919
    int layer = blockIdx.y;
    int n = idx & 127, k = idx >> 7;             // k 0..639
    const float* basis = layer ? basis2 : basis1;
    const float* root  = layer ? root2  : root1;
    float v = (k < 512) ? basis[((k & 3) << 14) + ((k >> 2) << 7) + n]
                        : root[((k - 512) << 7) + n];
    unsigned short h = f2bf(v);
    unsigned short l = f2bf(v - bf2f(h));
    unsigned short* Bh = layer ? Bt2h : Bt1h;
    unsigned short* Bl = layer ? Bt2l : Bt1l;
    Bh[(size_t)n * 640 + k] = h;
    Bl[(size_t)n * 640 + k] = l;
}

// ---------------- CSR build ----------------
__global__ __launch_bounds__(256) void hist_kernel(
    const int* __restrict__ edge_index, int* __restrict__ deg, int E)
{
    int e = blockIdx.x * 256 + threadIdx.x;
    if (e < E) atomicAdd(&deg[edge_index[E + e]], 1);
}

// scanA: per-block (1024) local exclusive scan of deg -> row_start, block totals
__global__ __launch_bounds__(1024) void scanA_kernel(
    const int* __restrict__ deg, int* __restrict__ row_start,
    int* __restrict__ btot, int N)
{
    __shared__ int wtot[16];
    __shared__ int woff[16];
    const int tid = threadIdx.x, lane = tid & 63, wid = tid >> 6;
    int i = blockIdx.x * 1024 + tid;
    int v = (i < N) ? deg[i] : 0;
    int x = v;
    #pragma unroll
    for (int d = 1; d < 64; d <<= 1) {
        int t = __shfl_up(x, d, 64);
        if (lane >= d) x += t;
    }
    if (lane == 63) wtot[wid] = x;
    __syncthreads();
    if (wid == 0 && lane < 16) {
        int s = wtot[lane];
        int y = s;
        #pragma unroll
        for (int d = 1; d < 16; d <<= 1) {
            int t = __shfl_up(y, d, 16);
            if (lane >= d) y += t;
        }
        woff[lane] = y - s;
        if (lane == 15) btot[blockIdx.x] = y;
    }
    __syncthreads();
    if (i < N) row_start[i] = woff[wid] + (x - v);
}

// scanB: one wave scans <=64 block totals -> boff (exclusive); writes row_start[N]
__global__ __launch_bounds__(64) void scanB_kernel(
    const int* __restrict__ btot, int* __restrict__ boff,
    int* __restrict__ row_start, int nB, int N)
{
    int t = threadIdx.x;
    int v = (t < nB) ? btot[t] : 0;
    int x = v;
    #pragma unroll
    for (int d = 1; d < 64; d <<= 1) {
        int u = __shfl_up(x, d, 64);
        if (t >= d) x += u;
    }
    if (t < nB) boff[t] = x - v;
    if (t == nB - 1) row_start[N] = x;
}

// scanC: add block offsets; init cursor
__global__ __launch_bounds__(1024) void scanC_kernel(
    int* __restrict__ row_start, int* __restrict__ cursor,
    const int* __restrict__ boff, int N)
{
    int i = blockIdx.x * 1024 + threadIdx.x;
    if (i < N) {
        int r = row_start[i] + boff[blockIdx.x];
        row_start[i] = r;
        cursor[i]    = r;
    }
}

__global__ __launch_bounds__(256) void fill_kernel(
    const int* __restrict__ edge_index, const int* __restrict__ edge_type,
    const float* __restrict__ edge_norm, int* __restrict__ cursor,
    int* __restrict__ src_s, int* __restrict__ et_s, float* __restrict__ norm_s, int E)
{
    int e = blockIdx.x * 256 + threadIdx.x;
    if (e >= E) return;
    int dst = edge_index[E + e];
    int pos = atomicAdd(&cursor[dst], 1);
    src_s[pos]  = edge_index[e];
    et_s[pos]   = edge_type[e];
    norm_s[pos] = edge_norm[e];
}

// ---------------- edge agg -> w bf16 [N,512], k = 4d+b ----------------
__global__ __launch_bounds__(256) void edge_agg_kernel(
    const float* __restrict__ X,
    const int* __restrict__ row_start,
    const int* __restrict__ src_s, const int* __restrict__ et_s,
    const float* __restrict__ norm_s,
    const float* __restrict__ att,      // [R,4]
    unsigned short* __restrict__ w, int N)
{
    int n = blockIdx.x * 8 + (threadIdx.x >> 5);
    if (n >= N) return;
    int l = threadIdx.x & 31;           // dims 4l..4l+3
    int s0 = row_start[n], s1 = row_start[n + 1];
    float acc[4][4];
    #pragma unroll
    for (int d = 0; d < 4; ++d)
        #pragma unroll
        for (int b = 0; b < 4; ++b) acc[d][b] = 0.f;
    for (int p = s0; p < s1; ++p) {
        int   src  = src_s[p];
        int   et   = et_s[p];
        float norm = norm_s[p];
        float4 a = *(const float4*)(att + (size_t)et * 4);
        a.x *= norm; a.y *= norm; a.z *= norm; a.w *= norm;
        float4 x = *(const float4*)&X[(size_t)src * 128 + (l << 2)];
        float xs[4] = {x.x, x.y, x.z, x.w};
        #pragma unroll
        for (int d = 0; d < 4; ++d) {
            acc[d][0] = fmaf(a.x, xs[d], acc[d][0]);
            acc[d][1] = fmaf(a.y, xs[d], acc[d][1]);
            acc[d][2] = fmaf(a.z, xs[d], acc[d][2]);
            acc[d][3] = fmaf(a.w, xs[d], acc[d][3]);
        }
    }
    float inv = 1.0f / fmaxf((float)(s1 - s0), 1.0f);
    #pragma unroll
    for (int d = 0; d < 4; ++d) {
        ushort4 h;
        h.x = f2bf(acc[d][0] * inv);
        h.y = f2bf(acc[d][1] * inv);
        h.z = f2bf(acc[d][2] * inv);
        h.w = f2bf(acc[d][3] * inv);
        *(ushort4*)&w[(size_t)n * 512 + (l << 4) + (d << 2)] = h;
    }
}

// ---------------- GEMM K=640, split-bf16 MFMA ----------------
// A = [w(bf16, k<512) | X(fp32 split, k>=512)], B = Bt^T (pre-split hi/lo).
// k<512 chunks: acc += aH*bL + aH*bH (w already bf16, no lo part).
// k>=512 chunks: acc += aL*bH + aH*bL + aH*bH.
__global__ __launch_bounds__(256) void gemm640_kernel(
    const unsigned short* __restrict__ wbf,   // [N,512] bf16
    const float* __restrict__ X,              // [N,128]
    const unsigned short* __restrict__ Bth,   // [128][640] bf16 hi
    const unsigned short* __restrict__ Btl,   // [128][640] bf16 lo
    const float* __restrict__ bias,
    float* __restrict__ Xout, int N)
{
    __shared__ unsigned short A_hi[64 * 40];
    __shared__ unsigned short A_lo[64 * 40];
    __shared__ unsigned short B_hi[128 * 40];
    __shared__ unsigned short B_lo[128 * 40];

    const int tid  = threadIdx.x;
    const int row0 = blockIdx.x * 64;
    const int lane = tid & 63, wv = tid >> 6;
    const int ml   = lane & 15, quad = lane >> 4;

    f4v acc[8];
    #pragma unroll
    for (int t = 0; t < 8; ++t) acc[t] = (f4v){0.f, 0.f, 0.f, 0.f};

    for (int kc = 0; kc < 20; ++kc) {
        const int k0 = kc * 32;
        if (kc) __syncthreads();

        if (k0 < 512) {
            // A: 64 rows x 32 k bf16 straight copy (8 bf16/thread)
            int r  = tid >> 2;
            int kv = (tid & 3) << 3;
            int gr = row0 + r;
            us8 v = {0, 0, 0, 0, 0, 0, 0, 0};
            if (gr < N) v = *(const us8*)&wbf[(size_t)gr * 512 + k0 + kv];
            *(us8*)&A_hi[r * 40 + kv] = v;
        } else {
            // A: 64 rows x 32 k fp32 -> split hi/lo bf16
            #pragma unroll
            for (int i = 0; i < 2; ++i) {
                int idx = tid + i * 256;
                int r = idx >> 3, kv = (idx & 7) << 2;
                int gr = row0 + r;
                float4 v = make_float4(0.f, 0.f, 0.f, 0.f);
                if (gr < N)
                    v = *(const float4*)&X[(size_t)gr * 128 + (k0 - 512) + kv];
                ushort4 h, l;
                h.x = f2bf(v.x); l.x = f2bf(v.x - bf2f(h.x));
                h.y = f2bf(v.y); l.y = f2bf(v.y - bf2f(h.y));
                h.z = f2bf(v.z); l.z = f2bf(v.z - bf2f(h.z));
                h.w = f2bf(v.w); l.w = f2bf(v.w - bf2f(h.w));
                *(ushort4*)&A_hi[r * 40 + kv] = h;
                *(ushort4*)&A_lo[r * 40 + kv] = l;
            }
        }
        // B: 128 n x 32 k, straight bf16 copy (hi & lo)
        #pragma unroll
        for (int i = 0; i < 2; ++i) {
            int idx = tid + i * 256;          // 0..511
            int n = idx >> 2, kv = (idx & 3) << 3;
            *(us8*)&B_hi[n * 40 + kv] = *(const us8*)&Bth[(size_t)n * 640 + k0 + kv];
            *(us8*)&B_lo[n * 40 + kv] = *(const us8*)&Btl[(size_t)n * 640 + k0 + kv];
        }
        __syncthreads();

        s8v aH = *(const s8v*)&A_hi[(wv * 16 + ml) * 40 + quad * 8];
        if (k0 < 512) {
            #pragma unroll
            for (int t = 0; t < 8; ++t) {
                s8v bH = *(const s8v*)&B_hi[(t * 16 + ml) * 40 + quad * 8];
                s8v bL = *(const s8v*)&B_lo[(t * 16 + ml) * 40 + quad * 8];
                acc[t] = __builtin_amdgcn_mfma_f32_16x16x32_bf16(aH, bL, acc[t], 0, 0, 0);
                acc[t] = __builtin_amdgcn_mfma_f32_16x16x32_bf16(aH, bH, acc[t], 0, 0, 0);
            }
        } else {
            s8v aL = *(const s8v*)&A_lo[(wv * 16 + ml) * 40 + quad * 8];
            #pragma unroll
            for (int t = 0; t < 8; ++t) {
                s8v bH = *(const s8v*)&B_hi[(t * 16 + ml) * 40 + quad * 8];
                s8v bL = *(const s8v*)&B_lo[(t * 16 + ml) * 40 + quad * 8];
                acc[t] = __builtin_amdgcn_mfma_f32_16x16x32_bf16(aL, bH, acc[t], 0, 0, 0);
                acc[t] = __builtin_amdgcn_mfma_f32_16x16x32_bf16(aH, bL, acc[t], 0, 0, 0);
                acc[t] = __builtin_amdgcn_mfma_f32_16x16x32_bf16(aH, bH, acc[t], 0, 0, 0);
            }
        }
    }

    // epilogue: C/D layout col=lane&15, row=quad*4+reg
    #pragma unroll
    for (int t = 0; t < 8; ++t) {
        float bv = bias[t * 16 + ml];
        #pragma unroll
        for (int j = 0; j < 4; ++j) {
            int gr = row0 + wv * 16 + quad * 4 + j;
            if (gr < N)
                Xout[(size_t)gr * 128 + t * 16 + ml] = fmaxf(acc[t][j] + bv, 0.f);
        }
    }
}

// ---------------- relation context: R2 = relu(DAD @ tab @ W) ----------------
// 512 threads: o = t&127, q = t>>7 splits the K loops 4-way; LDS reduce.
__global__ __launch_bounds__(512) void relctx_kernel(
    const float* __restrict__ DAD,
    const float* __restrict__ tab,
    const float* __restrict__ W,
    float* __restrict__ R2, int NR)
{
    __shared__ float part[4][128];
    __shared__ float r1s[128];
    int r = blockIdx.x;
    int t = threadIdx.x;
    int o = t & 127, q = t >> 7;
    float s = 0.f;
    #pragma unroll 4
    for (int j = q; j < NR; j += 4)
        s = fmaf(DAD[r * NR + j], tab[j * 128 + o], s);
    part[q][o] = s;
    __syncthreads();
    if (t < 128) r1s[t] = part[0][t] + part[1][t] + part[2][t] + part[3][t];
    __syncthreads();
    float s2 = 0.f;
    #pragma unroll 8
    for (int k = q * 32; k < q * 32 + 32; ++k)
        s2 = fmaf(r1s[k], W[k * 128 + o], s2);
    part[q][o] = s2;
    __syncthreads();
    if (t < 128)
        R2[r * 128 + t] = fmaxf(part[0][t] + part[1][t] + part[2][t] + part[3][t], 0.f);
}

// ---------------- gated output ----------------
__global__ __launch_bounds__(256) void output_kernel(
    const int* __restrict__ samples,
    const float* __restrict__ gate_e,
    const float* __restrict__ gate_r,
    const float* __restrict__ ent_emb,
    const float* __restrict__ rel_emb,
    const float* __restrict__ ctx2,
    const float* __restrict__ relctx,
    float* __restrict__ out, int S)
{
    int s = blockIdx.x * 2 + (threadIdx.x >> 7);
    if (s >= S) return;
    int p = blockIdx.y;
    int o = threadIdx.x & 127;
    float v;
    if (p == 1) {
        int idx = samples[s * 3 + 1];
        float g = 1.0f / (1.0f + __expf(-gate_r[o]));
        v = g * rel_emb[idx * 128 + o] + (1.0f - g) * relctx[idx * 128 + o];
    } else {
        int idx = samples[s * 3 + (p == 0 ? 0 : 2)];
        float g = 1.0f / (1.0f + __expf(-gate_e[o]));
        v = g * ent_emb[(size_t)idx * 128 + o] + (1.0f - g) * ctx2[(size_t)idx * 128 + o];
    }
    out[(size_t)p * S * 128 + (size_t)s * 128 + o] = v;
}

extern "C" void kernel_launch(void* const* d_in, const int* in_sizes, int n_in,
                              void* d_out, int out_size, void* d_ws, size_t ws_size,
                              hipStream_t stream)
{
    const int*   entity     = (const int*)d_in[0];
    const int*   edge_index = (const int*)d_in[1];
    const int*   edge_type  = (const int*)d_in[2];
    const float* edge_norm  = (const float*)d_in[3];
    const int*   samples    = (const int*)d_in[4];
    const float* DAD        = (const float*)d_in[5];
    const float* ent_emb    = (const float*)d_in[6];
    const float* rel_emb    = (const float*)d_in[7];
    const float* ent_tab    = (const float*)d_in[8];
    const float* rel_tab    = (const float*)d_in[9];
    const float* Wrel       = (const float*)d_in[10];
    const float* gate_e     = (const float*)d_in[11];
    const float* gate_r     = (const float*)d_in[12];
    const float* basis1     = (const float*)d_in[13];
    const float* att1       = (const float*)d_in[14];
    const float* root1      = (const float*)d_in[15];
    const float* bias1      = (const float*)d_in[16];
    const float* basis2     = (const float*)d_in[17];
    const float* att2       = (const float*)d_in[18];
    const float* root2      = (const float*)d_in[19];
    const float* bias2      = (const float*)d_in[20];

    const int N  = in_sizes[0];        // 50000
    const int E  = in_sizes[2];        // 200000
    const int S  = in_sizes[4] / 3;    // 20000
    const int NR = in_sizes[9] / 128;  // 200

    float* ws      = (float*)d_ws;
    float* X0      = ws;                               // [N,128] f32
    float* X1      = X0 + (size_t)N * 128;             // [N,128] f32
    unsigned short* wbf = (unsigned short*)(X1 + (size_t)N * 128); // [N,512] bf16
    float* Rc      = (float*)(wbf + (size_t)N * 512);  // [NR,128] f32
    int*   deg     = (int*)(Rc + (size_t)NR * 128);    // [N]
    int*   rstart  = deg + N;                          // [N+1]
    int*   cursor  = rstart + N + 1;                   // [N]
    int*   src_s   = cursor + N;                       // [E]
    int*   et_s    = src_s + E;                        // [E]
    float* norm_s  = (float*)(et_s + E);               // [E]
    int*   btot    = (int*)(norm_s + E);               // [64]
    int*   boff    = btot + 64;                        // [64]
    uintptr_t bt   = ((uintptr_t)(boff + 64) + 15) & ~(uintptr_t)15;
    unsigned short* Bt1h = (unsigned short*)bt;        // [128*640] each
    unsigned short* Bt1l = Bt1h + 128 * 640;
    unsigned short* Bt2h = Bt1l + 128 * 640;
    unsigned short* Bt2l = Bt2h + 128 * 640;

    const int egrid = (E + 255) / 256;
    const int ggrid = (N + 63) / 64;
    const int agrid = (N + 7) / 8;
    const int nB    = (N + 1023) / 1024;

    // ---- weight prep + CSR build ----
    bprep_kernel<<<dim3(320, 2), 256, 0, stream>>>(basis1, root1, basis2, root2,
                                                   Bt1h, Bt1l, Bt2h, Bt2l);
    hipMemsetAsync(deg, 0, (size_t)N * sizeof(int), stream);
    hist_kernel<<<egrid, 256, 0, stream>>>(edge_index, deg, E);
    scanA_kernel<<<nB, 1024, 0, stream>>>(deg, rstart, btot, N);
    scanB_kernel<<<1, 64, 0, stream>>>(btot, boff, rstart, nB, N);
    scanC_kernel<<<nB, 1024, 0, stream>>>(rstart, cursor, boff, N);
    fill_kernel<<<egrid, 256, 0, stream>>>(edge_index, edge_type, edge_norm, cursor,
                                           src_s, et_s, norm_s, E);

    // ---- X0 = ent_tab[entity] ----
    x0_kernel<<<(N * 32 + 255) / 256, 256, 0, stream>>>(ent_tab, entity, X0, N);

    // ---- layer 1: X1 = relu([agg(X0)|X0] @ W1) ----
    edge_agg_kernel<<<agrid, 256, 0, stream>>>(X0, rstart, src_s, et_s, norm_s, att1, wbf, N);
    gemm640_kernel<<<ggrid, 256, 0, stream>>>(wbf, X0, Bt1h, Bt1l, bias1, X1, N);

    // ---- layer 2: X0 = relu([agg(X1)|X1] @ W2) ----
    edge_agg_kernel<<<agrid, 256, 0, stream>>>(X1, rstart, src_s, et_s, norm_s, att2, wbf, N);
    gemm640_kernel<<<ggrid, 256, 0, stream>>>(wbf, X1, Bt2h, Bt2l, bias2, X0, N);

    // ---- relation context ----
    relctx_kernel<<<NR, 512, 0, stream>>>(DAD, rel_tab, Wrel, Rc, NR);

    // ---- gated output ----
    output_kernel<<<dim3((S + 1) / 2, 3), 256, 0, stream>>>(
        samples, gate_e, gate_r, ent_emb, rel_emb, X0, Rc, (float*)d_out, S);
}